// Round 1
// baseline (73.657 us; speedup 1.0000x reference)
//
#include <hip/hip_runtime.h>
#include <math.h>

// ---- compile-time problem constants (from setup_inputs) ----
#define B_SZ 2
#define HI 48
#define WI 48
#define NG (HI*WI)          // 2304 gaussians per image
#define NT (B_SZ*NG)        // 4608 total gaussians
#define FD 65               // feat dim (64 conv + factor)
#define HIDN 256
#define HT 96
#define WT 96
#define PT (HT*WT)          // 9216 pixels per image
#define FACTOR 2.0f         // max(96/48, 96/48)
#define OFF_SCALE 0.125f    // 3 * (2*factor / max(Ht,Wt))
#define A_MIN (1.0f/255.0f)
#define A_MAX 0.99f

#define GPB 8               // gaussians per block in param kernel
#define CH 144              // gaussians per chunk in render kernel
#define NCHUNK 16           // 2304 / 144

// params SoA layout in ws: [8][NT]: px, py, conA, conB, conC, r, g, b

__global__ __launch_bounds__(256) void param_kernel(
    const float* __restrict__ inp, const float* __restrict__ enc_w, const float* __restrict__ enc_b,
    const float* __restrict__ ow1, const float* __restrict__ ob1, const float* __restrict__ ow2, const float* __restrict__ ob2,
    const float* __restrict__ sw1, const float* __restrict__ sb1, const float* __restrict__ sw2, const float* __restrict__ sb2,
    const float* __restrict__ rw1, const float* __restrict__ rb1, const float* __restrict__ rw2, const float* __restrict__ rb2,
    const float* __restrict__ cw1, const float* __restrict__ cb1, const float* __restrict__ cw2, const float* __restrict__ cb2,
    float* __restrict__ params)
{
    __shared__ float feat[GPB][FD];
    __shared__ float hid[4][GPB][HIDN + 1];   // +1 pad: layer-2 column reads hit all 32 banks
    __shared__ float red[256];
    __shared__ float outv[GPB][8];

    const int t  = threadIdx.x;
    const int n0 = blockIdx.x * GPB;

    // ---- conv 3x3 SAME (64 out channels), 8 gaussians: 512 (gi,o) tasks ----
    for (int rep = 0; rep < 2; ++rep) {
        int idx = rep * 256 + t;
        int gi = idx >> 6, o = idx & 63;
        int n = n0 + gi;
        int b = n / NG, pix = n % NG;
        int y = pix / WI, x = pix % WI;
        float acc = enc_b[o];
        for (int c = 0; c < 3; ++c) {
            for (int ky = 0; ky < 3; ++ky) {
                int yy = y + ky - 1;
                if (yy < 0 || yy >= HI) continue;
                for (int kx = 0; kx < 3; ++kx) {
                    int xx = x + kx - 1;
                    if (xx < 0 || xx >= WI) continue;
                    acc += inp[((b*3 + c)*HI + yy)*WI + xx] * enc_w[((o*3 + c)*3 + ky)*3 + kx];
                }
            }
        }
        feat[gi][o] = acc;
    }
    if (t < GPB) feat[t][64] = FACTOR;
    __syncthreads();

    // ---- layer 1: hidden unit t of 4 MLPs for GPB gaussians (weights reused x8) ----
    float acc0[GPB], acc1[GPB], acc2[GPB], acc3[GPB];
    #pragma unroll
    for (int gi = 0; gi < GPB; ++gi) { acc0[gi]=0.f; acc1[gi]=0.f; acc2[gi]=0.f; acc3[gi]=0.f; }
    for (int k = 0; k < FD; ++k) {
        float w0 = ow1[k*HIDN + t];
        float w1 = sw1[k*HIDN + t];
        float w2 = rw1[k*HIDN + t];
        float w3 = cw1[k*HIDN + t];
        #pragma unroll
        for (int gi = 0; gi < GPB; ++gi) {
            float f = feat[gi][k];
            acc0[gi] += w0*f; acc1[gi] += w1*f; acc2[gi] += w2*f; acc3[gi] += w3*f;
        }
    }
    {
        float bb0 = ob1[t], bb1 = sb1[t], bb2 = rb1[t], bb3 = cb1[t];
        #pragma unroll
        for (int gi = 0; gi < GPB; ++gi) {
            hid[0][gi][t] = fmaxf(acc0[gi] + bb0, 0.f);
            hid[1][gi][t] = fmaxf(acc1[gi] + bb1, 0.f);
            hid[2][gi][t] = fmaxf(acc2[gi] + bb2, 0.f);
            hid[3][gi][t] = fmaxf(acc3[gi] + bb3, 0.f);
        }
    }
    __syncthreads();

    // ---- layer 2: 64 (gi,o) dot-256, 4-way k split ----
    {
        int o = t & 7, gi = (t >> 3) & 7, q = t >> 6;
        int m, od, j;
        const float* w2p;
        if (o < 2)      { m = 0; od = 2; j = o;     w2p = ow2; }
        else if (o < 4) { m = 1; od = 2; j = o - 2; w2p = sw2; }
        else if (o < 5) { m = 2; od = 1; j = 0;     w2p = rw2; }
        else            { m = 3; od = 3; j = o - 5; w2p = cw2; }
        float p = 0.f;
        int k0 = q * 64;
        for (int k = k0; k < k0 + 64; ++k) p += hid[m][gi][k] * w2p[k*od + j];
        red[t] = p;
    }
    __syncthreads();
    if (t < 64) {
        int o = t & 7, gi = t >> 3;
        float v = red[t] + red[t+64] + red[t+128] + red[t+192];
        float b2 = (o < 2) ? ob2[o] : (o < 4) ? sb2[o-2] : (o < 5) ? rb2[0] : cb2[o-5];
        outv[gi][o] = v + b2;
    }
    __syncthreads();

    // ---- activations + projection + conic, one thread per gaussian ----
    if (t < GPB) {
        int gi = t, n = n0 + gi;
        int pix = n % NG;
        int y = pix / WI, x = pix % WI;
        float cy = -1.f + (2.f*y + 1.f) / (float)HI;
        float cx = -1.f + (2.f*x + 1.f) / (float)WI;
        float xyy = cy + tanhf(outv[gi][0]) * OFF_SCALE;
        float xyx = cx + tanhf(outv[gi][1]) * OFF_SCALE;
        float pxp = (xyx + 1.f) * 0.5f * (float)WT - 0.5f;
        float pyp = (xyy + 1.f) * 0.5f * (float)HT - 0.5f;
        float t2 = outv[gi][2], t3 = outv[gi][3];
        float s0 = (t2 > 0.f ? t2 : expf(t2) - 1.f) + 1.5f;
        float s1 = (t3 > 0.f ? t3 : expf(t3) - 1.f) + 1.5f;
        float rot = tanhf(outv[gi][4]) * 3.14159265358979323846f;
        float cr = cosf(rot), sr = sinf(rot);
        float sx2 = s0*s0, sy2 = s1*s1;
        float cov_a = cr*cr*sx2 + sr*sr*sy2;
        float cov_b = cr*sr*(sx2 - sy2);
        float cov_c = sr*sr*sx2 + cr*cr*sy2;
        float det = cov_a*cov_c - cov_b*cov_b;
        float conA = cov_c / det, conB = -cov_b / det, conC = cov_a / det;
        float c0 = 1.f/(1.f + expf(-outv[gi][5]));
        float c1 = 1.f/(1.f + expf(-outv[gi][6]));
        float c2 = 1.f/(1.f + expf(-outv[gi][7]));
        params[0*NT + n] = pxp;
        params[1*NT + n] = pyp;
        params[2*NT + n] = conA;
        params[3*NT + n] = conB;
        params[4*NT + n] = conC;
        params[5*NT + n] = c0;
        params[6*NT + n] = c1;
        params[7*NT + n] = c2;
    }
}

__global__ __launch_bounds__(256) void render_kernel(const float* __restrict__ params,
                                                     float* __restrict__ acc)
{
    __shared__ float4 lp0[CH];   // px, py, conA, conB
    __shared__ float4 lp1[CH];   // conC, r, g, b
    const int t  = threadIdx.x;
    const int b  = blockIdx.z;
    const int g0 = blockIdx.y * CH;

    for (int i = t; i < CH; i += 256) {
        int n = b*NG + g0 + i;
        lp0[i] = make_float4(params[0*NT + n], params[1*NT + n], params[2*NT + n], params[3*NT + n]);
        lp1[i] = make_float4(params[4*NT + n], params[5*NT + n], params[6*NT + n], params[7*NT + n]);
    }
    __syncthreads();

    const int p = blockIdx.x * 256 + t;
    const float gxf = (float)(p % WT);
    const float gyf = (float)(p / WT);
    float ra = 0.f, ga = 0.f, ba = 0.f, aa = 0.f;
    #pragma unroll 4
    for (int i = 0; i < CH; ++i) {
        float4 c0 = lp0[i];
        float4 c1 = lp1[i];
        float dx = gxf - c0.x, dy = gyf - c0.y;
        float sigma = 0.5f*(c0.z*dx*dx + c1.x*dy*dy) + c0.w*(dx*dy);
        float w = __expf(-sigma);
        bool keep = (sigma >= 0.f) && (w >= A_MIN);
        float alpha = keep ? fminf(w, A_MAX) : 0.f;
        ra += alpha * c1.y;
        ga += alpha * c1.z;
        ba += alpha * c1.w;
        aa += alpha;
    }
    float* dst = acc + (size_t)(b*PT + p)*4;
    atomicAdd(dst + 0, ra);
    atomicAdd(dst + 1, ga);
    atomicAdd(dst + 2, ba);
    atomicAdd(dst + 3, aa);
}

__global__ __launch_bounds__(256) void finalize_kernel(const float* __restrict__ acc,
                                                       float* __restrict__ out)
{
    int i = blockIdx.x * 256 + threadIdx.x;   // 0 .. B*PT-1
    float4 v = ((const float4*)acc)[i];
    float T = fminf(fmaxf(1.f - v.w, 0.f), 1.f);
    out[i*3 + 0] = v.x + T;
    out[i*3 + 1] = v.y + T;
    out[i*3 + 2] = v.z + T;
}

extern "C" void kernel_launch(void* const* d_in, const int* in_sizes, int n_in,
                              void* d_out, int out_size, void* d_ws, size_t ws_size,
                              hipStream_t stream)
{
    const float* inp   = (const float*)d_in[0];
    const float* enc_w = (const float*)d_in[1];
    const float* enc_b = (const float*)d_in[2];
    const float* ow1 = (const float*)d_in[3];
    const float* ob1 = (const float*)d_in[4];
    const float* ow2 = (const float*)d_in[5];
    const float* ob2 = (const float*)d_in[6];
    const float* sw1 = (const float*)d_in[7];
    const float* sb1 = (const float*)d_in[8];
    const float* sw2 = (const float*)d_in[9];
    const float* sb2 = (const float*)d_in[10];
    const float* rw1 = (const float*)d_in[11];
    const float* rb1 = (const float*)d_in[12];
    const float* rw2 = (const float*)d_in[13];
    const float* rb2 = (const float*)d_in[14];
    const float* cw1 = (const float*)d_in[15];
    const float* cb1 = (const float*)d_in[16];
    const float* cw2 = (const float*)d_in[17];
    const float* cb2 = (const float*)d_in[18];
    // d_in[19], d_in[20]: target_h/target_w == 96 (compile-time constants here)

    float* params = (float*)d_ws;                 // 8*NT floats = 147456 B
    float* acc    = params + 8*NT;                // B*PT*4 floats = 294912 B

    hipMemsetAsync(acc, 0, (size_t)B_SZ*PT*4*sizeof(float), stream);

    param_kernel<<<NT/GPB, 256, 0, stream>>>(inp, enc_w, enc_b,
                                             ow1, ob1, ow2, ob2,
                                             sw1, sb1, sw2, sb2,
                                             rw1, rb1, rw2, rb2,
                                             cw1, cb1, cw2, cb2,
                                             params);
    render_kernel<<<dim3(PT/256, NCHUNK, B_SZ), 256, 0, stream>>>(params, acc);
    finalize_kernel<<<(B_SZ*PT)/256, 256, 0, stream>>>(acc, (float*)d_out);
}